// Round 1
// baseline (191.462 us; speedup 1.0000x reference)
//
#include <hip/hip_runtime.h>

#define HW 16384
#define CIN 64
#define COUT 64
#define KK 9
#define HH 128
#define WW 128
#define NB 4

// ---------------- transpose x: [N][C][HW] -> [N][HW][C] ----------------
__global__ __launch_bounds__(256) void transpose_x_kernel(
    const float* __restrict__ x, float* __restrict__ xt) {
  __shared__ float tile[64][65];
  const int n = blockIdx.y;
  const int hw0 = blockIdx.x * 64;
  const int tx = threadIdx.x & 63;
  const int ty = threadIdx.x >> 6;
  const float* xp = x + (size_t)n * CIN * HW;
  #pragma unroll
  for (int c = ty; c < 64; c += 4)
    tile[c][tx] = xp[(size_t)c * HW + hw0 + tx];
  __syncthreads();
  float* xtp = xt + (size_t)n * HW * CIN;
  #pragma unroll
  for (int hw = ty; hw < 64; hw += 4)
    xtp[(size_t)(hw0 + hw) * CIN + tx] = tile[tx][hw];
}

// ------------- transpose w: [o][c][k] -> [(k*64+c)][o] -----------------
__global__ void transpose_w_kernel(const float* __restrict__ w,
                                   float* __restrict__ wt) {
  const int i = blockIdx.x * 256 + threadIdx.x;
  if (i >= 576 * 64) return;
  const int o = i & 63;
  const int t = i >> 6;      // t = k*64 + c
  const int c = t & 63;
  const int k = t >> 6;
  wt[i] = w[((size_t)o * 64 + c) * 9 + k];
}

// ---------------- main deform-conv kernel ------------------------------
// block = 256 threads = 4 waves; each wave owns 4 pixels.
// Phase 1: lane = input channel, sample 9 taps per pixel into LDS.
// Phase 2: lane = output channel, dot-product over 576 (k,c) pairs.
template <bool TRANS>
__global__ __launch_bounds__(256) void deform_main(
    const float* __restrict__ xsrc, const float* __restrict__ offset,
    const float* __restrict__ wsrc, float* __restrict__ out) {
  __shared__ float s[16][576];
  const int wave = threadIdx.x >> 6;
  const int lane = threadIdx.x & 63;
  const int p0 = blockIdx.x * 16;

  #pragma unroll
  for (int i = 0; i < 4; ++i) {
    const int p = p0 + wave * 4 + i;
    const int n = p >> 14;
    const int rem = p & 16383;
    const int y = rem >> 7;
    const int x = rem & 127;
    const float* off = offset + (size_t)n * 18 * HW + rem;
    const float* xb = TRANS ? (xsrc + (size_t)n * HW * CIN)
                            : (xsrc + (size_t)n * CIN * HW);
    #pragma unroll
    for (int k = 0; k < KK; ++k) {
      const float dy = off[(size_t)(2 * k) * HW];
      const float dx = off[(size_t)(2 * k + 1) * HW];
      const float py = (float)(y - 1 + k / 3) + dy;
      const float px = (float)(x - 1 + k % 3) + dx;
      const float y0f = floorf(py);
      const float x0f = floorf(px);
      const float ly = py - y0f;
      const float lx = px - x0f;
      const int y0 = (int)y0f, x0 = (int)x0f;
      const int y1 = y0 + 1, x1 = x0 + 1;
      const bool vy0 = (y0 >= 0) && (y0 < HH);
      const bool vy1 = (y1 >= 0) && (y1 < HH);
      const bool vx0 = (x0 >= 0) && (x0 < WW);
      const bool vx1 = (x1 >= 0) && (x1 < WW);
      const int cy0 = min(max(y0, 0), HH - 1);
      const int cy1 = min(max(y1, 0), HH - 1);
      const int cx0 = min(max(x0, 0), WW - 1);
      const int cx1 = min(max(x1, 0), WW - 1);
      float v00, v01, v10, v11;
      if (TRANS) {
        v00 = (vy0 && vx0) ? xb[((size_t)(cy0 * WW + cx0)) * CIN + lane] : 0.f;
        v01 = (vy0 && vx1) ? xb[((size_t)(cy0 * WW + cx1)) * CIN + lane] : 0.f;
        v10 = (vy1 && vx0) ? xb[((size_t)(cy1 * WW + cx0)) * CIN + lane] : 0.f;
        v11 = (vy1 && vx1) ? xb[((size_t)(cy1 * WW + cx1)) * CIN + lane] : 0.f;
      } else {
        v00 = (vy0 && vx0) ? xb[(size_t)lane * HW + cy0 * WW + cx0] : 0.f;
        v01 = (vy0 && vx1) ? xb[(size_t)lane * HW + cy0 * WW + cx1] : 0.f;
        v10 = (vy1 && vx0) ? xb[(size_t)lane * HW + cy1 * WW + cx0] : 0.f;
        v11 = (vy1 && vx1) ? xb[(size_t)lane * HW + cy1 * WW + cx1] : 0.f;
      }
      const float sv = v00 * (1.f - ly) * (1.f - lx) + v01 * (1.f - ly) * lx +
                       v10 * ly * (1.f - lx) + v11 * ly * lx;
      s[wave * 4 + i][k * 64 + lane] = sv;
    }
  }
  __syncthreads();

  float acc0 = 0.f, acc1 = 0.f, acc2 = 0.f, acc3 = 0.f;
  const int pb = wave * 4;
  #pragma unroll 4
  for (int t = 0; t < 576; ++t) {
    float wv;
    if (TRANS) {
      wv = wsrc[(size_t)t * 64 + lane];
    } else {
      const int c = t & 63;
      const int k = t >> 6;
      wv = wsrc[((size_t)lane * 64 + c) * 9 + k];
    }
    acc0 += s[pb + 0][t] * wv;
    acc1 += s[pb + 1][t] * wv;
    acc2 += s[pb + 2][t] * wv;
    acc3 += s[pb + 3][t] * wv;
  }

  const float acc[4] = {acc0, acc1, acc2, acc3};
  #pragma unroll
  for (int i = 0; i < 4; ++i) {
    const int p = p0 + pb + i;
    const int n = p >> 14;
    const int rem = p & 16383;
    out[((size_t)n * COUT + lane) * HW + rem] = acc[i];
  }
}

extern "C" void kernel_launch(void* const* d_in, const int* in_sizes, int n_in,
                              void* d_out, int out_size, void* d_ws,
                              size_t ws_size, hipStream_t stream) {
  const float* x = (const float*)d_in[0];
  const float* offset = (const float*)d_in[1];
  const float* weight = (const float*)d_in[2];
  float* out = (float*)d_out;

  const size_t xt_elems = (size_t)NB * HW * CIN;
  const size_t wt_elems = (size_t)576 * 64;
  const size_t need = (xt_elems + wt_elems) * sizeof(float);

  const int n_pix = NB * HW;            // 65536
  const int blocks = n_pix / 16;        // 4096

  if (ws_size >= need) {
    float* xt = (float*)d_ws;
    float* wt = xt + xt_elems;
    dim3 g1(HW / 64, NB);
    transpose_x_kernel<<<g1, 256, 0, stream>>>(x, xt);
    transpose_w_kernel<<<(576 * 64 + 255) / 256, 256, 0, stream>>>(weight, wt);
    deform_main<true><<<blocks, 256, 0, stream>>>(xt, offset, wt, out);
  } else {
    deform_main<false><<<blocks, 256, 0, stream>>>(x, offset, weight, out);
  }
}

// Round 2
// 91.440 us; speedup vs baseline: 2.0939x; 2.0939x over previous
//
#include <hip/hip_runtime.h>

#define HW 16384
#define CIN 64
#define COUT 64
#define HH 128
#define WW 128
#define NB 4

typedef __attribute__((ext_vector_type(8))) short bf16x8;
typedef __attribute__((ext_vector_type(4))) float f32x4;

__device__ __forceinline__ unsigned short f32_bf16(float f) {
  unsigned u = __builtin_bit_cast(unsigned, f);
  u += 0x7fffu + ((u >> 16) & 1u);
  return (unsigned short)(u >> 16);
}

// ---------------- transpose x: [N][C][HW] -> [N][HW][C] (fp32) ----------
__global__ __launch_bounds__(256) void transpose_x_kernel(
    const float* __restrict__ x, float* __restrict__ xt) {
  __shared__ float tile[64][65];
  const int n = blockIdx.y;
  const int hw0 = blockIdx.x * 64;
  const int tx = threadIdx.x & 63;
  const int ty = threadIdx.x >> 6;
  const float* xp = x + (size_t)n * CIN * HW;
  #pragma unroll
  for (int c = ty; c < 64; c += 4)
    tile[c][tx] = xp[(size_t)c * HW + hw0 + tx];
  __syncthreads();
  float* xtp = xt + (size_t)n * HW * CIN;
  #pragma unroll
  for (int hw = ty; hw < 64; hw += 4)
    xtp[(size_t)(hw0 + hw) * CIN + tx] = tile[tx][hw];
}

// ------- transpose w: [o][c][k] -> bf16 [o][k*64+c]  (row-major 576) ----
__global__ void transpose_w_kernel(const float* __restrict__ w,
                                   unsigned short* __restrict__ wt) {
  const int i = blockIdx.x * 256 + threadIdx.x;
  if (i >= 64 * 576) return;
  const int o = i / 576;
  const int t = i % 576;      // t = k*64 + c
  const int c = t & 63;
  const int k = t >> 6;
  wt[i] = f32_bf16(w[((size_t)o * 64 + c) * 9 + k]);
}

// ---------------- main: sample -> LDS(bf16) -> MFMA -> store ------------
// block = 256 threads = 4 waves; 16 pixels per block.
// Phase 1: lane = input channel; each wave samples 4 pixels x 9 taps.
// Phase 2: GEMM C[16 pix][64 oc] = S[16][576] * W^T[576][64] via
//          mfma_f32_16x16x32_bf16, one 16x16 oc-tile per wave, 18 K-steps.
__global__ __launch_bounds__(256) void deform_mfma(
    const float* __restrict__ xt, const float* __restrict__ offset,
    const unsigned short* __restrict__ wt, float* __restrict__ out) {
  __shared__ unsigned short s[16][584];   // 584 = 576 + 8 pad (bank stagger)
  const int tid = threadIdx.x;
  const int wave = tid >> 6;
  const int lane = tid & 63;
  const int p0 = blockIdx.x * 16;
  const int n = p0 >> 14;
  const int rem0 = p0 & 16383;

  // ---- phase 1: bilinear sampling into LDS as bf16 ----
  const float* xb = xt + (size_t)n * HW * CIN;
  const float* offb = offset + (size_t)n * 18 * HW;
  for (int i = 0; i < 4; ++i) {
    const int pix = wave * 4 + i;
    const int rem = rem0 + pix;
    const int y = rem >> 7;
    const int x = rem & 127;
    #pragma unroll
    for (int k = 0; k < 9; ++k) {
      const float dy = offb[(size_t)(2 * k) * HW + rem];
      const float dx = offb[(size_t)(2 * k + 1) * HW + rem];
      const float py = (float)(y - 1 + k / 3) + dy;
      const float px = (float)(x - 1 + k % 3) + dx;
      const float y0f = floorf(py);
      const float x0f = floorf(px);
      const float ly = py - y0f;
      const float lx = px - x0f;
      const int y0 = (int)y0f, x0 = (int)x0f;
      const int y1 = y0 + 1, x1 = x0 + 1;
      const bool vy0 = (y0 >= 0) && (y0 < HH);
      const bool vy1 = (y1 >= 0) && (y1 < HH);
      const bool vx0 = (x0 >= 0) && (x0 < WW);
      const bool vx1 = (x1 >= 0) && (x1 < WW);
      const int cy0 = min(max(y0, 0), HH - 1);
      const int cy1 = min(max(y1, 0), HH - 1);
      const int cx0 = min(max(x0, 0), WW - 1);
      const int cx1 = min(max(x1, 0), WW - 1);
      const float v00 = (vy0 && vx0) ? xb[((size_t)(cy0 * WW + cx0)) * CIN + lane] : 0.f;
      const float v01 = (vy0 && vx1) ? xb[((size_t)(cy0 * WW + cx1)) * CIN + lane] : 0.f;
      const float v10 = (vy1 && vx0) ? xb[((size_t)(cy1 * WW + cx0)) * CIN + lane] : 0.f;
      const float v11 = (vy1 && vx1) ? xb[((size_t)(cy1 * WW + cx1)) * CIN + lane] : 0.f;
      const float sv = v00 * (1.f - ly) * (1.f - lx) + v01 * (1.f - ly) * lx +
                       v10 * ly * (1.f - lx) + v11 * ly * lx;
      s[pix][k * 64 + lane] = f32_bf16(sv);
    }
  }
  __syncthreads();

  // ---- phase 2: MFMA contraction ----
  f32x4 acc = {0.f, 0.f, 0.f, 0.f};
  const int arow = lane & 15;            // A row = pixel; D col = oc
  const int kg = (lane >> 4) * 8;        // k-group base
  const unsigned short* ap = &s[arow][kg];
  const unsigned short* bp = wt + ((size_t)(wave * 16 + arow)) * 576 + kg;
  #pragma unroll
  for (int t0 = 0; t0 < 576; t0 += 32) {
    bf16x8 av = *(const bf16x8*)(ap + t0);
    bf16x8 bv = *(const bf16x8*)(bp + t0);
    acc = __builtin_amdgcn_mfma_f32_16x16x32_bf16(av, bv, acc, 0, 0, 0);
  }
  __syncthreads();   // all A-reads of s done before aliasing as s2

  // ---- transpose C through LDS, coalesced store ----
  float* s2 = (float*)&s[0][0];          // [64][17] fp32 (4352 B, aliases s)
  {
    const int oc = wave * 16 + (lane & 15);
    const int mb = (lane >> 4) * 4;
    #pragma unroll
    for (int j = 0; j < 4; ++j)
      s2[oc * 17 + mb + j] = acc[j];
  }
  __syncthreads();
  const int pix = tid & 15;
  const int ocg = tid >> 4;
  float* ob = out + (size_t)n * COUT * HW + rem0 + pix;
  #pragma unroll
  for (int r = 0; r < 4; ++r) {
    const int oc = ocg + 16 * r;
    ob[(size_t)oc * HW] = s2[oc * 17 + pix];
  }
}

// ---------------- fp32 fallback (ws too small) --------------------------
__global__ __launch_bounds__(256) void deform_fallback(
    const float* __restrict__ xsrc, const float* __restrict__ offset,
    const float* __restrict__ wsrc, float* __restrict__ out) {
  __shared__ float s[16][576];
  const int wave = threadIdx.x >> 6;
  const int lane = threadIdx.x & 63;
  const int p0 = blockIdx.x * 16;
  for (int i = 0; i < 4; ++i) {
    const int p = p0 + wave * 4 + i;
    const int n = p >> 14;
    const int rem = p & 16383;
    const int y = rem >> 7;
    const int x = rem & 127;
    const float* off = offset + (size_t)n * 18 * HW + rem;
    const float* xb = xsrc + (size_t)n * CIN * HW;
    #pragma unroll
    for (int k = 0; k < 9; ++k) {
      const float dy = off[(size_t)(2 * k) * HW];
      const float dx = off[(size_t)(2 * k + 1) * HW];
      const float py = (float)(y - 1 + k / 3) + dy;
      const float px = (float)(x - 1 + k % 3) + dx;
      const float y0f = floorf(py), x0f = floorf(px);
      const float ly = py - y0f, lx = px - x0f;
      const int y0 = (int)y0f, x0 = (int)x0f;
      const int y1 = y0 + 1, x1 = x0 + 1;
      const bool vy0 = (y0 >= 0) && (y0 < HH), vy1 = (y1 >= 0) && (y1 < HH);
      const bool vx0 = (x0 >= 0) && (x0 < WW), vx1 = (x1 >= 0) && (x1 < WW);
      const int cy0 = min(max(y0, 0), HH - 1), cy1 = min(max(y1, 0), HH - 1);
      const int cx0 = min(max(x0, 0), WW - 1), cx1 = min(max(x1, 0), WW - 1);
      const float v00 = (vy0 && vx0) ? xb[(size_t)lane * HW + cy0 * WW + cx0] : 0.f;
      const float v01 = (vy0 && vx1) ? xb[(size_t)lane * HW + cy0 * WW + cx1] : 0.f;
      const float v10 = (vy1 && vx0) ? xb[(size_t)lane * HW + cy1 * WW + cx0] : 0.f;
      const float v11 = (vy1 && vx1) ? xb[(size_t)lane * HW + cy1 * WW + cx1] : 0.f;
      s[wave * 4 + i][k * 64 + lane] =
          v00 * (1.f - ly) * (1.f - lx) + v01 * (1.f - ly) * lx +
          v10 * ly * (1.f - lx) + v11 * ly * lx;
    }
  }
  __syncthreads();
  float a0 = 0.f, a1 = 0.f, a2 = 0.f, a3 = 0.f;
  const int pb = wave * 4;
  for (int t = 0; t < 576; ++t) {
    const int c = t & 63;
    const int k = t >> 6;
    const float wv = wsrc[((size_t)lane * 64 + c) * 9 + k];
    a0 += s[pb + 0][t] * wv;
    a1 += s[pb + 1][t] * wv;
    a2 += s[pb + 2][t] * wv;
    a3 += s[pb + 3][t] * wv;
  }
  const float acc[4] = {a0, a1, a2, a3};
  for (int i = 0; i < 4; ++i) {
    const int p = p0 + pb + i;
    const int n = p >> 14;
    const int rem = p & 16383;
    out[((size_t)n * COUT + lane) * HW + rem] = acc[i];
  }
}

extern "C" void kernel_launch(void* const* d_in, const int* in_sizes, int n_in,
                              void* d_out, int out_size, void* d_ws,
                              size_t ws_size, hipStream_t stream) {
  const float* x = (const float*)d_in[0];
  const float* offset = (const float*)d_in[1];
  const float* weight = (const float*)d_in[2];
  float* out = (float*)d_out;

  const size_t xt_elems = (size_t)NB * HW * CIN;       // 4.19e6 fp32
  const size_t wt_elems = (size_t)64 * 576;            // bf16
  const size_t need = xt_elems * sizeof(float) + wt_elems * sizeof(short);

  const int blocks = NB * HW / 16;                     // 4096

  if (ws_size >= need) {
    float* xt = (float*)d_ws;
    unsigned short* wt = (unsigned short*)(xt + xt_elems);
    dim3 g1(HW / 64, NB);
    transpose_x_kernel<<<g1, 256, 0, stream>>>(x, xt);
    transpose_w_kernel<<<(64 * 576 + 255) / 256, 256, 0, stream>>>(weight, wt);
    deform_mfma<<<blocks, 256, 0, stream>>>(xt, offset, wt, out);
  } else {
    deform_fallback<<<blocks, 256, 0, stream>>>(x, offset, weight, out);
  }
}

// Round 4
// 67.161 us; speedup vs baseline: 2.8508x; 1.3615x over previous
//
#include <hip/hip_runtime.h>

#define HW 16384
#define CIN 64
#define COUT 64
#define HH 128
#define WW 128
#define NB 4

typedef __attribute__((ext_vector_type(8))) short bf16x8;
typedef __attribute__((ext_vector_type(4))) float f32x4;
typedef __attribute__((ext_vector_type(4))) unsigned short u16x4;

__device__ __forceinline__ unsigned short f32_bf16(float f) {
  unsigned u = __builtin_bit_cast(unsigned, f);
  u += 0x7fffu + ((u >> 16) & 1u);
  return (unsigned short)(u >> 16);
}
__device__ __forceinline__ float bf16_f32(unsigned short h) {
  return __builtin_bit_cast(float, (unsigned)h << 16);
}

// -------- transpose x: [N][C][HW] -> bf16 [N][HW][C] --------------------
__global__ __launch_bounds__(256) void transpose_x_kernel(
    const float* __restrict__ x, unsigned short* __restrict__ xt) {
  __shared__ float tile[64][65];
  const int n = blockIdx.y;
  const int hw0 = blockIdx.x * 64;
  const int tx = threadIdx.x & 63;
  const int ty = threadIdx.x >> 6;
  const float* xp = x + (size_t)n * CIN * HW;
  #pragma unroll
  for (int c = ty; c < 64; c += 4)
    tile[c][tx] = xp[(size_t)c * HW + hw0 + tx];
  __syncthreads();
  unsigned short* xtp = xt + (size_t)n * HW * CIN;
  #pragma unroll
  for (int hw = ty; hw < 64; hw += 4)
    xtp[(size_t)(hw0 + hw) * CIN + tx] = f32_bf16(tile[tx][hw]);
}

// -------- transpose w: [o][c][k] -> bf16 [o][k*64+c] --------------------
__global__ void transpose_w_kernel(const float* __restrict__ w,
                                   unsigned short* __restrict__ wt) {
  const int i = blockIdx.x * 256 + threadIdx.x;
  if (i >= 64 * 576) return;
  const int o = i / 576;
  const int t = i % 576;      // t = k*64 + c
  const int c = t & 63;
  const int k = t >> 6;
  wt[i] = f32_bf16(w[((size_t)o * 64 + c) * 9 + k]);
}

// -------- main: sample (4 px in parallel per wave) -> MFMA -> store -----
// block = 256 threads = 4 waves = 16 pixels.
// Phase 1: lane-group g (16 lanes) owns pixel wave*4+g; each lane gathers
//          4 channels per tap as one 8B bf16x4 load.
// Phase 2: C[16 pix][64 oc] = S[16][576] * W^T via mfma_16x16x32_bf16,
//          one 16-oc tile per wave, 18 K-steps; direct f32x4 store.
__global__ __launch_bounds__(256) void deform_mfma(
    const unsigned short* __restrict__ xt, const float* __restrict__ offset,
    const unsigned short* __restrict__ wt, float* __restrict__ out) {
  __shared__ unsigned short s[16][584];   // 584: 16B-aligned rows
  __shared__ float soff[16][18];
  const int tid = threadIdx.x;
  const int wave = tid >> 6;
  const int lane = tid & 63;
  const int g = lane >> 4;
  const int li = lane & 15;
  const int p0 = blockIdx.x * 16;
  const int n = p0 >> 14;
  const int rem0 = p0 & 16383;

  // ---- stage offsets: 16 pixels x 18 values ----
  const float* offb = offset + (size_t)n * 18 * HW + rem0;
  for (int idx = tid; idx < 288; idx += 256) {
    const int j = idx >> 4;
    const int p = idx & 15;
    soff[p][j] = offb[(size_t)j * HW + p];
  }
  __syncthreads();

  // ---- phase 1: bilinear sampling, 4 pixels in parallel per wave ----
  const int pix = wave * 4 + g;
  const int rem = rem0 + pix;
  const int y = rem >> 7;
  const int x = rem & 127;
  const unsigned short* xb = xt + (size_t)n * HW * CIN + li * 4;
  #pragma unroll
  for (int k = 0; k < 9; ++k) {
    const float dy = soff[pix][2 * k];
    const float dx = soff[pix][2 * k + 1];
    const float fy = floorf(dy);
    const float fx = floorf(dx);
    const float ly = dy - fy;
    const float lx = dx - fx;
    const int y0 = y - 1 + (k / 3) + (int)fy;
    const int x0 = x - 1 + (k % 3) + (int)fx;
    const int y1 = y0 + 1, x1 = x0 + 1;
    const bool vy0 = (unsigned)y0 < (unsigned)HH;
    const bool vy1 = (unsigned)y1 < (unsigned)HH;
    const bool vx0 = (unsigned)x0 < (unsigned)WW;
    const bool vx1 = (unsigned)x1 < (unsigned)WW;
    const int cy0 = min(max(y0, 0), HH - 1);
    const int cy1 = min(max(y1, 0), HH - 1);
    const int cx0 = min(max(x0, 0), WW - 1);
    const int cx1 = min(max(x1, 0), WW - 1);
    const float w00 = (vy0 && vx0) ? (1.f - ly) * (1.f - lx) : 0.f;
    const float w01 = (vy0 && vx1) ? (1.f - ly) * lx : 0.f;
    const float w10 = (vy1 && vx0) ? ly * (1.f - lx) : 0.f;
    const float w11 = (vy1 && vx1) ? ly * lx : 0.f;
    const u16x4 u00 = *(const u16x4*)(xb + (size_t)(cy0 * WW + cx0) * CIN);
    const u16x4 u01 = *(const u16x4*)(xb + (size_t)(cy0 * WW + cx1) * CIN);
    const u16x4 u10 = *(const u16x4*)(xb + (size_t)(cy1 * WW + cx0) * CIN);
    const u16x4 u11 = *(const u16x4*)(xb + (size_t)(cy1 * WW + cx1) * CIN);
    u16x4 pv;
    #pragma unroll
    for (int c = 0; c < 4; ++c) {
      const float sv = bf16_f32(u00[c]) * w00 + bf16_f32(u01[c]) * w01 +
                       bf16_f32(u10[c]) * w10 + bf16_f32(u11[c]) * w11;
      pv[c] = f32_bf16(sv);
    }
    *(u16x4*)&s[pix][k * 64 + li * 4] = pv;
  }
  __syncthreads();

  // ---- phase 2: MFMA contraction ----
  f32x4 acc = {0.f, 0.f, 0.f, 0.f};
  const unsigned short* ap = &s[li][g * 8];            // A row = pixel
  const unsigned short* bp = wt + ((size_t)(wave * 16 + li)) * 576 + g * 8;
  #pragma unroll
  for (int t0 = 0; t0 < 576; t0 += 32) {
    bf16x8 av = *(const bf16x8*)(ap + t0);
    bf16x8 bv = *(const bf16x8*)(bp + t0);
    acc = __builtin_amdgcn_mfma_f32_16x16x32_bf16(av, bv, acc, 0, 0, 0);
  }

  // ---- direct store: lane holds pixels g*4..g*4+3 of oc=wave*16+li ----
  const int oc = wave * 16 + li;
  float* ob = out + ((size_t)n * COUT + oc) * HW + rem0 + g * 4;
  *(f32x4*)ob = acc;
}

// ---------------- fp32 fallback (ws too small) --------------------------
__global__ __launch_bounds__(256) void deform_fallback(
    const float* __restrict__ xsrc, const float* __restrict__ offset,
    const float* __restrict__ wsrc, float* __restrict__ out) {
  __shared__ float s[16][576];
  const int wave = threadIdx.x >> 6;
  const int lane = threadIdx.x & 63;
  const int p0 = blockIdx.x * 16;
  for (int i = 0; i < 4; ++i) {
    const int p = p0 + wave * 4 + i;
    const int n = p >> 14;
    const int rem = p & 16383;
    const int y = rem >> 7;
    const int x = rem & 127;
    const float* off = offset + (size_t)n * 18 * HW + rem;
    const float* xb = xsrc + (size_t)n * CIN * HW;
    #pragma unroll
    for (int k = 0; k < 9; ++k) {
      const float dy = off[(size_t)(2 * k) * HW];
      const float dx = off[(size_t)(2 * k + 1) * HW];
      const float py = (float)(y - 1 + k / 3) + dy;
      const float px = (float)(x - 1 + k % 3) + dx;
      const float y0f = floorf(py), x0f = floorf(px);
      const float ly = py - y0f, lx = px - x0f;
      const int y0 = (int)y0f, x0 = (int)x0f;
      const int y1 = y0 + 1, x1 = x0 + 1;
      const bool vy0 = (y0 >= 0) && (y0 < HH), vy1 = (y1 >= 0) && (y1 < HH);
      const bool vx0 = (x0 >= 0) && (x0 < WW), vx1 = (x1 >= 0) && (x1 < WW);
      const int cy0 = min(max(y0, 0), HH - 1), cy1 = min(max(y1, 0), HH - 1);
      const int cx0 = min(max(x0, 0), WW - 1), cx1 = min(max(x1, 0), WW - 1);
      const float v00 = (vy0 && vx0) ? xb[(size_t)lane * HW + cy0 * WW + cx0] : 0.f;
      const float v01 = (vy0 && vx1) ? xb[(size_t)lane * HW + cy0 * WW + cx1] : 0.f;
      const float v10 = (vy1 && vx0) ? xb[(size_t)lane * HW + cy1 * WW + cx0] : 0.f;
      const float v11 = (vy1 && vx1) ? xb[(size_t)lane * HW + cy1 * WW + cx1] : 0.f;
      s[wave * 4 + i][k * 64 + lane] =
          v00 * (1.f - ly) * (1.f - lx) + v01 * (1.f - ly) * lx +
          v10 * ly * (1.f - lx) + v11 * ly * lx;
    }
  }
  __syncthreads();
  float a0 = 0.f, a1 = 0.f, a2 = 0.f, a3 = 0.f;
  const int pb = wave * 4;
  for (int t = 0; t < 576; ++t) {
    const int c = t & 63;
    const int k = t >> 6;
    const float wv = wsrc[((size_t)lane * 64 + c) * 9 + k];
    a0 += s[pb + 0][t] * wv;
    a1 += s[pb + 1][t] * wv;
    a2 += s[pb + 2][t] * wv;
    a3 += s[pb + 3][t] * wv;
  }
  const float acc[4] = {a0, a1, a2, a3};
  for (int i = 0; i < 4; ++i) {
    const int p = p0 + pb + i;
    const int n = p >> 14;
    const int rem = p & 16383;
    out[((size_t)n * COUT + lane) * HW + rem] = acc[i];
  }
}

extern "C" void kernel_launch(void* const* d_in, const int* in_sizes, int n_in,
                              void* d_out, int out_size, void* d_ws,
                              size_t ws_size, hipStream_t stream) {
  const float* x = (const float*)d_in[0];
  const float* offset = (const float*)d_in[1];
  const float* weight = (const float*)d_in[2];
  float* out = (float*)d_out;

  const size_t xt_elems = (size_t)NB * HW * CIN;       // bf16
  const size_t wt_elems = (size_t)64 * 576;            // bf16
  const size_t need = (xt_elems + wt_elems) * sizeof(short);

  const int blocks = NB * HW / 16;                     // 4096

  if (ws_size >= need) {
    unsigned short* xtp = (unsigned short*)d_ws;
    unsigned short* wtp = xtp + xt_elems;
    dim3 g1(HW / 64, NB);
    transpose_x_kernel<<<g1, 256, 0, stream>>>(x, xtp);
    transpose_w_kernel<<<(64 * 576 + 255) / 256, 256, 0, stream>>>(weight, wtp);
    deform_mfma<<<blocks, 256, 0, stream>>>(xtp, offset, wtp, out);
  } else {
    deform_fallback<<<blocks, 256, 0, stream>>>(x, offset, weight, out);
  }
}

// Round 6
// 62.892 us; speedup vs baseline: 3.0443x; 1.0679x over previous
//
#include <hip/hip_runtime.h>

#define HW 16384
#define CIN 64
#define COUT 64
#define HH 128
#define WW 128
#define NB 4
#define PXB 32

typedef __attribute__((ext_vector_type(8))) short bf16x8;
typedef __attribute__((ext_vector_type(4))) float f32x4;
typedef __attribute__((ext_vector_type(4))) unsigned short u16x4;

__device__ __forceinline__ unsigned short f32_bf16(float f) {
  unsigned u = __builtin_bit_cast(unsigned, f);
  u += 0x7fffu + ((u >> 16) & 1u);
  return (unsigned short)(u >> 16);
}
__device__ __forceinline__ float bf16_f32(unsigned short h) {
  return __builtin_bit_cast(float, (unsigned)h << 16);
}

// ---- fused prep: blocks [0,1024) transpose x; [1024,1168) transpose w ----
// x: [N][C][HW] -> bf16 [N][HW][C];  w: [o][c][k] -> bf16 [o][k*64+c]
__global__ __launch_bounds__(256) void prep_kernel(
    const float* __restrict__ x, const float* __restrict__ w,
    unsigned short* __restrict__ xt, unsigned short* __restrict__ wt) {
  __shared__ float tile[64][65];
  const int bid = blockIdx.x;
  if (bid < 1024) {
    const int n = bid >> 8;
    const int hw0 = (bid & 255) * 64;
    const int tx = threadIdx.x & 63;
    const int ty = threadIdx.x >> 6;
    const float* xp = x + (size_t)n * CIN * HW;
    #pragma unroll
    for (int c = ty; c < 64; c += 4)
      tile[c][tx] = xp[(size_t)c * HW + hw0 + tx];
    __syncthreads();
    unsigned short* xtp = xt + (size_t)n * HW * CIN;
    #pragma unroll
    for (int hw = ty; hw < 64; hw += 4)
      xtp[(size_t)(hw0 + hw) * CIN + tx] = f32_bf16(tile[tx][hw]);
  } else {
    const int i = (bid - 1024) * 256 + threadIdx.x;
    if (i < 64 * 576) {
      const int o = i / 576;
      const int t = i % 576;          // t = k*64 + c
      const int c = t & 63;
      const int k = t >> 6;
      wt[i] = f32_bf16(w[((size_t)o * 64 + c) * 9 + k]);
    }
  }
}

// ---- main: batched-gather sampling -> LDS(bf16) -> MFMA -> store --------
// block = 256 thr = 4 waves = 32 pixels.
// Phase 1 (x2 rounds): lane-group g(16 lanes) owns one pixel; all 9 taps'
//   36 corner loads issued together (register arrays force MLP), then blend.
// Phase 2: C[32 px][64 oc]; wave w -> oc w*16..+15, two 16x16 px tiles,
//   B-frag loaded once per K-step, reused for both tiles.
__global__ __launch_bounds__(256, 4) void deform_mfma(
    const unsigned short* __restrict__ xt, const float* __restrict__ offset,
    const unsigned short* __restrict__ wt, float* __restrict__ out) {
  __shared__ unsigned short s[PXB][584];
  __shared__ float soff[PXB][18];
  const int tid = threadIdx.x;
  const int wave = tid >> 6;
  const int lane = tid & 63;
  const int g = lane >> 4;
  const int li = lane & 15;
  const int p0 = blockIdx.x * PXB;
  const int n = p0 >> 14;
  const int rem0 = p0 & 16383;

  // stage offsets: 32 px x 18 values, coalesced
  const float* offb = offset + (size_t)n * 18 * HW + rem0;
  for (int idx = tid; idx < PXB * 18; idx += 256) {
    const int j = idx >> 5;
    const int p = idx & 31;
    soff[p][j] = offb[(size_t)j * HW + p];
  }
  __syncthreads();

  const unsigned short* xb = xt + (size_t)n * HW * CIN + li * 4;

  #pragma unroll 1
  for (int r = 0; r < 2; ++r) {
    const int pix = wave * 8 + r * 4 + g;
    const int rem = rem0 + pix;
    const int y = rem >> 7;
    const int x = rem & 127;
    float W00[9], W01[9], W10[9], W11[9];
    u16x4 V00[9], V01[9], V10[9], V11[9];
    #pragma unroll
    for (int k = 0; k < 9; ++k) {
      const float dy = soff[pix][2 * k];
      const float dx = soff[pix][2 * k + 1];
      const float fy = floorf(dy);
      const float fx = floorf(dx);
      const float ly = dy - fy;
      const float lx = dx - fx;
      const int y0 = y - 1 + (k / 3) + (int)fy;
      const int x0 = x - 1 + (k % 3) + (int)fx;
      const int y1 = y0 + 1, x1 = x0 + 1;
      const bool vy0 = (unsigned)y0 < (unsigned)HH;
      const bool vy1 = (unsigned)y1 < (unsigned)HH;
      const bool vx0 = (unsigned)x0 < (unsigned)WW;
      const bool vx1 = (unsigned)x1 < (unsigned)WW;
      const int cy0 = min(max(y0, 0), HH - 1);
      const int cy1 = min(max(y1, 0), HH - 1);
      const int cx0 = min(max(x0, 0), WW - 1);
      const int cx1 = min(max(x1, 0), WW - 1);
      W00[k] = (vy0 && vx0) ? (1.f - ly) * (1.f - lx) : 0.f;
      W01[k] = (vy0 && vx1) ? (1.f - ly) * lx : 0.f;
      W10[k] = (vy1 && vx0) ? ly * (1.f - lx) : 0.f;
      W11[k] = (vy1 && vx1) ? ly * lx : 0.f;
      V00[k] = *(const u16x4*)(xb + (size_t)(cy0 * WW + cx0) * CIN);
      V01[k] = *(const u16x4*)(xb + (size_t)(cy0 * WW + cx1) * CIN);
      V10[k] = *(const u16x4*)(xb + (size_t)(cy1 * WW + cx0) * CIN);
      V11[k] = *(const u16x4*)(xb + (size_t)(cy1 * WW + cx1) * CIN);
    }
    __builtin_amdgcn_sched_barrier(0);   // keep all 36 loads in flight
    #pragma unroll
    for (int k = 0; k < 9; ++k) {
      u16x4 pv;
      #pragma unroll
      for (int c = 0; c < 4; ++c) {
        const float sv =
            bf16_f32(V00[k][c]) * W00[k] + bf16_f32(V01[k][c]) * W01[k] +
            bf16_f32(V10[k][c]) * W10[k] + bf16_f32(V11[k][c]) * W11[k];
        pv[c] = f32_bf16(sv);
      }
      *(u16x4*)&s[pix][k * 64 + li * 4] = pv;
    }
    __builtin_amdgcn_sched_barrier(0);   // don't hoist next round's loads
  }
  __syncthreads();

  // ---- phase 2: MFMA, one oc-tile per wave, two pixel tiles ----
  f32x4 acc0 = {0.f, 0.f, 0.f, 0.f};
  f32x4 acc1 = {0.f, 0.f, 0.f, 0.f};
  const unsigned short* ap0 = &s[li][g * 8];
  const unsigned short* ap1 = &s[16 + li][g * 8];
  const unsigned short* bp = wt + ((size_t)(wave * 16 + li)) * 576 + g * 8;
  #pragma unroll
  for (int t0 = 0; t0 < 576; t0 += 32) {
    bf16x8 bv = *(const bf16x8*)(bp + t0);
    bf16x8 a0 = *(const bf16x8*)(ap0 + t0);
    bf16x8 a1 = *(const bf16x8*)(ap1 + t0);
    acc0 = __builtin_amdgcn_mfma_f32_16x16x32_bf16(a0, bv, acc0, 0, 0, 0);
    acc1 = __builtin_amdgcn_mfma_f32_16x16x32_bf16(a1, bv, acc1, 0, 0, 0);
  }

  const int oc = wave * 16 + li;
  float* ob = out + ((size_t)n * COUT + oc) * HW + rem0 + g * 4;
  *(f32x4*)ob = acc0;
  *(f32x4*)(ob + 16) = acc1;
}

// ---------------- fp32 fallback (ws too small) --------------------------
__global__ __launch_bounds__(256) void deform_fallback(
    const float* __restrict__ xsrc, const float* __restrict__ offset,
    const float* __restrict__ wsrc, float* __restrict__ out) {
  __shared__ float s[16][576];
  const int wave = threadIdx.x >> 6;
  const int lane = threadIdx.x & 63;
  const int p0 = blockIdx.x * 16;
  for (int i = 0; i < 4; ++i) {
    const int p = p0 + wave * 4 + i;
    const int n = p >> 14;
    const int rem = p & 16383;
    const int y = rem >> 7;
    const int x = rem & 127;
    const float* off = offset + (size_t)n * 18 * HW + rem;
    const float* xb = xsrc + (size_t)n * CIN * HW;
    #pragma unroll
    for (int k = 0; k < 9; ++k) {
      const float dy = off[(size_t)(2 * k) * HW];
      const float dx = off[(size_t)(2 * k + 1) * HW];
      const float py = (float)(y - 1 + k / 3) + dy;
      const float px = (float)(x - 1 + k % 3) + dx;
      const float y0f = floorf(py), x0f = floorf(px);
      const float ly = py - y0f, lx = px - x0f;
      const int y0 = (int)y0f, x0 = (int)x0f;
      const int y1 = y0 + 1, x1 = x0 + 1;
      const bool vy0 = (y0 >= 0) && (y0 < HH), vy1 = (y1 >= 0) && (y1 < HH);
      const bool vx0 = (x0 >= 0) && (x0 < WW), vx1 = (x1 >= 0) && (x1 < WW);
      const int cy0 = min(max(y0, 0), HH - 1), cy1 = min(max(y1, 0), HH - 1);
      const int cx0 = min(max(x0, 0), WW - 1), cx1 = min(max(x1, 0), WW - 1);
      const float v00 = (vy0 && vx0) ? xb[(size_t)lane * HW + cy0 * WW + cx0] : 0.f;
      const float v01 = (vy0 && vx1) ? xb[(size_t)lane * HW + cy0 * WW + cx1] : 0.f;
      const float v10 = (vy1 && vx0) ? xb[(size_t)lane * HW + cy1 * WW + cx0] : 0.f;
      const float v11 = (vy1 && vx1) ? xb[(size_t)lane * HW + cy1 * WW + cx1] : 0.f;
      s[wave * 4 + i][k * 64 + lane] =
          v00 * (1.f - ly) * (1.f - lx) + v01 * (1.f - ly) * lx +
          v10 * ly * (1.f - lx) + v11 * ly * lx;
    }
  }
  __syncthreads();
  float a0 = 0.f, a1 = 0.f, a2 = 0.f, a3 = 0.f;
  const int pb = wave * 4;
  for (int t = 0; t < 576; ++t) {
    const int c = t & 63;
    const int k = t >> 6;
    const float wv = wsrc[((size_t)lane * 64 + c) * 9 + k];
    a0 += s[pb + 0][t] * wv;
    a1 += s[pb + 1][t] * wv;
    a2 += s[pb + 2][t] * wv;
    a3 += s[pb + 3][t] * wv;
  }
  const float acc[4] = {a0, a1, a2, a3};
  for (int i = 0; i < 4; ++i) {
    const int p = p0 + pb + i;
    const int n = p >> 14;
    const int rem = p & 16383;
    out[((size_t)n * COUT + lane) * HW + rem] = acc[i];
  }
}

extern "C" void kernel_launch(void* const* d_in, const int* in_sizes, int n_in,
                              void* d_out, int out_size, void* d_ws,
                              size_t ws_size, hipStream_t stream) {
  const float* x = (const float*)d_in[0];
  const float* offset = (const float*)d_in[1];
  const float* weight = (const float*)d_in[2];
  float* out = (float*)d_out;

  const size_t xt_elems = (size_t)NB * HW * CIN;       // bf16
  const size_t wt_elems = (size_t)64 * 576;            // bf16
  const size_t need = (xt_elems + wt_elems) * sizeof(short);

  if (ws_size >= need) {
    unsigned short* xtp = (unsigned short*)d_ws;
    unsigned short* wtp = xtp + xt_elems;
    prep_kernel<<<1024 + 144, 256, 0, stream>>>(x, weight, xtp, wtp);
    deform_mfma<<<NB * HW / PXB, 256, 0, stream>>>(xtp, offset, wtp, out);
  } else {
    deform_fallback<<<NB * HW / 16, 256, 0, stream>>>(x, offset, weight, out);
  }
}

// Round 7
// 56.581 us; speedup vs baseline: 3.3839x; 1.1115x over previous
//
#include <hip/hip_runtime.h>

#define HW 16384
#define CIN 64
#define COUT 64
#define HH 128
#define WW 128
#define NB 4
#define PXB 32

typedef __attribute__((ext_vector_type(8))) short bf16x8;
typedef __attribute__((ext_vector_type(4))) float f32x4;
typedef __attribute__((ext_vector_type(4))) unsigned short u16x4;

__device__ __forceinline__ unsigned short f32_bf16(float f) {
  unsigned u = __builtin_bit_cast(unsigned, f);
  u += 0x7fffu + ((u >> 16) & 1u);
  return (unsigned short)(u >> 16);
}
__device__ __forceinline__ float bf16_f32(unsigned short h) {
  return __builtin_bit_cast(float, (unsigned)h << 16);
}

// ---- fused prep: blocks [0,1024) transpose x; [1024,1168) transpose w ----
// x: [N][C][HW] -> bf16 [N][HW][C];  w: [o][c][k] -> bf16 [o][k*64+c]
__global__ __launch_bounds__(256) void prep_kernel(
    const float* __restrict__ x, const float* __restrict__ w,
    unsigned short* __restrict__ xt, unsigned short* __restrict__ wt) {
  __shared__ float tile[64][65];
  const int bid = blockIdx.x;
  if (bid < 1024) {
    const int n = bid >> 8;
    const int hw0 = (bid & 255) * 64;
    const int tx = threadIdx.x & 63;
    const int ty = threadIdx.x >> 6;
    const float* xp = x + (size_t)n * CIN * HW;
    #pragma unroll
    for (int c = ty; c < 64; c += 4)
      tile[c][tx] = xp[(size_t)c * HW + hw0 + tx];
    __syncthreads();
    unsigned short* xtp = xt + (size_t)n * HW * CIN;
    #pragma unroll
    for (int hw = ty; hw < 64; hw += 4)
      xtp[(size_t)(hw0 + hw) * CIN + tx] = f32_bf16(tile[tx][hw]);
  } else {
    const int i = (bid - 1024) * 256 + threadIdx.x;
    if (i < 64 * 576) {
      const int o = i / 576;
      const int t = i % 576;          // t = k*64 + c
      const int c = t & 63;
      const int k = t >> 6;
      wt[i] = f32_bf16(w[((size_t)o * 64 + c) * 9 + k]);
    }
  }
}

// ---- main: batched-gather sampling -> LDS(bf16) -> MFMA -> store --------
// block = 256 thr = 4 waves = 32 pixels.
// Phase 1 (x2 rounds): lane-group g(16 lanes) owns one pixel; all 9 taps'
//   36 corner loads issued together (register arrays force MLP), then blend.
//   NOTE: needs ~130-170 VGPR live -> launch_bounds min-waves=2 (cap 256);
//   the (256,4) cap at 128 VGPR caused scratch spills (WRITE_SIZE 70 MB).
// Phase 2: C[32 px][64 oc]; wave w -> oc w*16..+15, two 16x16 px tiles,
//   B-frag loaded once per K-step, reused for both tiles.
__global__ __launch_bounds__(256, 2) void deform_mfma(
    const unsigned short* __restrict__ xt, const float* __restrict__ offset,
    const unsigned short* __restrict__ wt, float* __restrict__ out) {
  __shared__ unsigned short s[PXB][584];
  __shared__ float soff[PXB][18];
  const int tid = threadIdx.x;
  const int wave = tid >> 6;
  const int lane = tid & 63;
  const int g = lane >> 4;
  const int li = lane & 15;
  const int p0 = blockIdx.x * PXB;
  const int n = p0 >> 14;
  const int rem0 = p0 & 16383;

  // stage offsets: 32 px x 18 values, coalesced
  const float* offb = offset + (size_t)n * 18 * HW + rem0;
  for (int idx = tid; idx < PXB * 18; idx += 256) {
    const int j = idx >> 5;
    const int p = idx & 31;
    soff[p][j] = offb[(size_t)j * HW + p];
  }
  __syncthreads();

  const unsigned short* xb = xt + (size_t)n * HW * CIN + li * 4;

  #pragma unroll 1
  for (int r = 0; r < 2; ++r) {
    const int pix = wave * 8 + r * 4 + g;
    const int rem = rem0 + pix;
    const int y = rem >> 7;
    const int x = rem & 127;
    float W00[9], W01[9], W10[9], W11[9];
    u16x4 V00[9], V01[9], V10[9], V11[9];
    #pragma unroll
    for (int k = 0; k < 9; ++k) {
      const float dy = soff[pix][2 * k];
      const float dx = soff[pix][2 * k + 1];
      const float fy = floorf(dy);
      const float fx = floorf(dx);
      const float ly = dy - fy;
      const float lx = dx - fx;
      const int y0 = y - 1 + (k / 3) + (int)fy;
      const int x0 = x - 1 + (k % 3) + (int)fx;
      const int y1 = y0 + 1, x1 = x0 + 1;
      const bool vy0 = (unsigned)y0 < (unsigned)HH;
      const bool vy1 = (unsigned)y1 < (unsigned)HH;
      const bool vx0 = (unsigned)x0 < (unsigned)WW;
      const bool vx1 = (unsigned)x1 < (unsigned)WW;
      const int cy0 = min(max(y0, 0), HH - 1);
      const int cy1 = min(max(y1, 0), HH - 1);
      const int cx0 = min(max(x0, 0), WW - 1);
      const int cx1 = min(max(x1, 0), WW - 1);
      W00[k] = (vy0 && vx0) ? (1.f - ly) * (1.f - lx) : 0.f;
      W01[k] = (vy0 && vx1) ? (1.f - ly) * lx : 0.f;
      W10[k] = (vy1 && vx0) ? ly * (1.f - lx) : 0.f;
      W11[k] = (vy1 && vx1) ? ly * lx : 0.f;
      V00[k] = *(const u16x4*)(xb + (size_t)(cy0 * WW + cx0) * CIN);
      V01[k] = *(const u16x4*)(xb + (size_t)(cy0 * WW + cx1) * CIN);
      V10[k] = *(const u16x4*)(xb + (size_t)(cy1 * WW + cx0) * CIN);
      V11[k] = *(const u16x4*)(xb + (size_t)(cy1 * WW + cx1) * CIN);
    }
    __builtin_amdgcn_sched_barrier(0);   // keep all 36 loads in flight
    #pragma unroll
    for (int k = 0; k < 9; ++k) {
      u16x4 pv;
      #pragma unroll
      for (int c = 0; c < 4; ++c) {
        const float sv =
            bf16_f32(V00[k][c]) * W00[k] + bf16_f32(V01[k][c]) * W01[k] +
            bf16_f32(V10[k][c]) * W10[k] + bf16_f32(V11[k][c]) * W11[k];
        pv[c] = f32_bf16(sv);
      }
      *(u16x4*)&s[pix][k * 64 + li * 4] = pv;
    }
    __builtin_amdgcn_sched_barrier(0);   // don't hoist next round's loads
  }
  __syncthreads();

  // ---- phase 2: MFMA, one oc-tile per wave, two pixel tiles ----
  f32x4 acc0 = {0.f, 0.f, 0.f, 0.f};
  f32x4 acc1 = {0.f, 0.f, 0.f, 0.f};
  const unsigned short* ap0 = &s[li][g * 8];
  const unsigned short* ap1 = &s[16 + li][g * 8];
  const unsigned short* bp = wt + ((size_t)(wave * 16 + li)) * 576 + g * 8;
  #pragma unroll
  for (int t0 = 0; t0 < 576; t0 += 32) {
    bf16x8 bv = *(const bf16x8*)(bp + t0);
    bf16x8 a0 = *(const bf16x8*)(ap0 + t0);
    bf16x8 a1 = *(const bf16x8*)(ap1 + t0);
    acc0 = __builtin_amdgcn_mfma_f32_16x16x32_bf16(a0, bv, acc0, 0, 0, 0);
    acc1 = __builtin_amdgcn_mfma_f32_16x16x32_bf16(a1, bv, acc1, 0, 0, 0);
  }

  const int oc = wave * 16 + li;
  float* ob = out + ((size_t)n * COUT + oc) * HW + rem0 + g * 4;
  *(f32x4*)ob = acc0;
  *(f32x4*)(ob + 16) = acc1;
}

// ---------------- fp32 fallback (ws too small) --------------------------
__global__ __launch_bounds__(256) void deform_fallback(
    const float* __restrict__ xsrc, const float* __restrict__ offset,
    const float* __restrict__ wsrc, float* __restrict__ out) {
  __shared__ float s[16][576];
  const int wave = threadIdx.x >> 6;
  const int lane = threadIdx.x & 63;
  const int p0 = blockIdx.x * 16;
  for (int i = 0; i < 4; ++i) {
    const int p = p0 + wave * 4 + i;
    const int n = p >> 14;
    const int rem = p & 16383;
    const int y = rem >> 7;
    const int x = rem & 127;
    const float* off = offset + (size_t)n * 18 * HW + rem;
    const float* xb = xsrc + (size_t)n * CIN * HW;
    #pragma unroll
    for (int k = 0; k < 9; ++k) {
      const float dy = off[(size_t)(2 * k) * HW];
      const float dx = off[(size_t)(2 * k + 1) * HW];
      const float py = (float)(y - 1 + k / 3) + dy;
      const float px = (float)(x - 1 + k % 3) + dx;
      const float y0f = floorf(py), x0f = floorf(px);
      const float ly = py - y0f, lx = px - x0f;
      const int y0 = (int)y0f, x0 = (int)x0f;
      const int y1 = y0 + 1, x1 = x0 + 1;
      const bool vy0 = (y0 >= 0) && (y0 < HH), vy1 = (y1 >= 0) && (y1 < HH);
      const bool vx0 = (x0 >= 0) && (x0 < WW), vx1 = (x1 >= 0) && (x1 < WW);
      const int cy0 = min(max(y0, 0), HH - 1), cy1 = min(max(y1, 0), HH - 1);
      const int cx0 = min(max(x0, 0), WW - 1), cx1 = min(max(x1, 0), WW - 1);
      const float v00 = (vy0 && vx0) ? xb[(size_t)lane * HW + cy0 * WW + cx0] : 0.f;
      const float v01 = (vy0 && vx1) ? xb[(size_t)lane * HW + cy0 * WW + cx1] : 0.f;
      const float v10 = (vy1 && vx0) ? xb[(size_t)lane * HW + cy1 * WW + cx0] : 0.f;
      const float v11 = (vy1 && vx1) ? xb[(size_t)lane * HW + cy1 * WW + cx1] : 0.f;
      s[wave * 4 + i][k * 64 + lane] =
          v00 * (1.f - ly) * (1.f - lx) + v01 * (1.f - ly) * lx +
          v10 * ly * (1.f - lx) + v11 * ly * lx;
    }
  }
  __syncthreads();
  float a0 = 0.f, a1 = 0.f, a2 = 0.f, a3 = 0.f;
  const int pb = wave * 4;
  for (int t = 0; t < 576; ++t) {
    const int c = t & 63;
    const int k = t >> 6;
    const float wv = wsrc[((size_t)lane * 64 + c) * 9 + k];
    a0 += s[pb + 0][t] * wv;
    a1 += s[pb + 1][t] * wv;
    a2 += s[pb + 2][t] * wv;
    a3 += s[pb + 3][t] * wv;
  }
  const float acc[4] = {a0, a1, a2, a3};
  for (int i = 0; i < 4; ++i) {
    const int p = p0 + pb + i;
    const int n = p >> 14;
    const int rem = p & 16383;
    out[((size_t)n * COUT + lane) * HW + rem] = acc[i];
  }
}

extern "C" void kernel_launch(void* const* d_in, const int* in_sizes, int n_in,
                              void* d_out, int out_size, void* d_ws,
                              size_t ws_size, hipStream_t stream) {
  const float* x = (const float*)d_in[0];
  const float* offset = (const float*)d_in[1];
  const float* weight = (const float*)d_in[2];
  float* out = (float*)d_out;

  const size_t xt_elems = (size_t)NB * HW * CIN;       // bf16
  const size_t wt_elems = (size_t)64 * 576;            // bf16
  const size_t need = (xt_elems + wt_elems) * sizeof(short);

  if (ws_size >= need) {
    unsigned short* xtp = (unsigned short*)d_ws;
    unsigned short* wtp = xtp + xt_elems;
    prep_kernel<<<1024 + 144, 256, 0, stream>>>(x, weight, xtp, wtp);
    deform_mfma<<<NB * HW / PXB, 256, 0, stream>>>(xtp, offset, wtp, out);
  } else {
    deform_fallback<<<NB * HW / 16, 256, 0, stream>>>(x, offset, weight, out);
  }
}